// Round 1
// baseline (126.266 us; speedup 1.0000x reference)
//
#include <hip/hip_runtime.h>

#define S_ 2500
#define CHUNKS 4
#define ITEMS_PER_BATCH (S_ * 8)                 // 20000 (s,h) items per batch
#define ITEMS_PER_CHUNK (ITEMS_PER_BATCH / CHUNKS) // 5000 (divisible by 8 and by 256-groups)

// Kernel 1: per (s,h) item, 8 lanes cooperate per position via shuffles.
// Each wave writes its partial pooled-sum (64 floats) to a private workspace slot.
__global__ __launch_bounds__(256) void attn_pool_k1(
    const float* __restrict__ sim,
    const float* __restrict__ wq, const float* __restrict__ bq,
    const float* __restrict__ wk, const float* __restrict__ bk,
    const float* __restrict__ wv, const float* __restrict__ bv,
    const float* __restrict__ pe,
    float* __restrict__ ws_part)
{
    const int b    = blockIdx.x >> 2;   // batch
    const int c    = blockIdx.x & 3;    // chunk of S
    const int tid  = threadIdx.x;
    const int lane = tid & 63;
    const int wave = tid >> 6;          // 0..3
    const int h    = tid & 7;           // head owned by this lane (invariant: 256%8==0, 5000%8==0)
    const int f0   = h * 8;
    const int srcBase = lane & 56;      // first lane of this position's 8-lane group

    // Loop-invariant weight slices for this lane's head (registers, no LDS).
    float wkr[8], bkr[8], dwr[8], dbr[8], wvr[8], bvr[8];
    #pragma unroll
    for (int d = 0; d < 8; ++d) {
        wkr[d] = wk[f0 + d];
        bkr[d] = bk[f0 + d];
        dwr[d] = wq[f0 + d] - wkr[d];   // q = k + x*(wq-wk) + (bq-bk)
        dbr[d] = bq[f0 + d] - bkr[d];
        wvr[d] = wv[f0 + d];
        bvr[d] = bv[f0 + d];
    }

    float acc[8];
    #pragma unroll
    for (int d = 0; d < 8; ++d) acc[d] = 0.f;

    const float* simb = sim + (size_t)b * S_;

    for (int i = c * ITEMS_PER_CHUNK + tid; i < (c + 1) * ITEMS_PER_CHUNK; i += 256) {
        const int s = i >> 3;
        const float x = simb[s];

        // pe slice for f = f0..f0+7 (coalesced: 8 lanes of a group cover 256B)
        const float4 p0 = *(const float4*)(pe + (size_t)s * 64 + f0);
        const float4 p1 = *(const float4*)(pe + (size_t)s * 64 + f0 + 4);
        const float pes[8] = {p0.x, p0.y, p0.z, p0.w, p1.x, p1.y, p1.z, p1.w};

        float kk[8], qq[8];
        #pragma unroll
        for (int d = 0; d < 8; ++d) {
            kk[d] = fmaf(x, wkr[d], bkr[d]) + pes[d];
            qq[d] = kk[d] + fmaf(x, dwr[d], dbr[d]);
        }

        // scores[h][t] = (q_h . k_t) / sqrt(8); k_t lives in lane srcBase+t
        float sc[8];
        #pragma unroll
        for (int t = 0; t < 8; ++t) {
            float dot = 0.f;
            #pragma unroll
            for (int d = 0; d < 8; ++d) {
                const float kv = __shfl(kk[d], srcBase + t, 64);
                dot = fmaf(qq[d], kv, dot);
            }
            sc[t] = dot * 0.35355339059327373f;
        }

        // softmax over t (thread-local, 8 values)
        float m = sc[0];
        #pragma unroll
        for (int t = 1; t < 8; ++t) m = fmaxf(m, sc[t]);
        float sum = 0.f;
        #pragma unroll
        for (int t = 0; t < 8; ++t) { sc[t] = __expf(sc[t] - m); sum += sc[t]; }
        const float inv = 1.0f / sum;
        #pragma unroll
        for (int t = 0; t < 8; ++t) sc[t] *= inv;

        // v slice owned by this lane: v[f0+d] = x*wv + bv   (no pe on v)
        float vv[8];
        #pragma unroll
        for (int d = 0; d < 8; ++d) vv[d] = fmaf(x, wvr[d], bvr[d]);

        // attended[h][d] = sum_t p[t] * v[t*8+d]; v_t lives in lane srcBase+t
        #pragma unroll
        for (int t = 0; t < 8; ++t) {
            const float pt = sc[t];
            #pragma unroll
            for (int d = 0; d < 8; ++d) {
                const float vtd = __shfl(vv[d], srcBase + t, 64);
                acc[d] = fmaf(pt, vtd, acc[d]);
            }
        }
    }

    // Reduce across the 8 lanes sharing this head within the wave (stride-8 lanes).
    #pragma unroll
    for (int d = 0; d < 8; ++d) {
        acc[d] += __shfl_down(acc[d], 32, 64);
        acc[d] += __shfl_down(acc[d], 16, 64);
        acc[d] += __shfl_down(acc[d],  8, 64);
    }

    // Lane h (<8) holds this wave's partial pooled sum for features f0..f0+7.
    if (lane < 8) {
        const int slot = blockIdx.x * 4 + wave;          // 4096 slots, batch b owns b*16..b*16+15
        float* dst = ws_part + (size_t)slot * 64 + f0;
        #pragma unroll
        for (int d = 0; d < 8; ++d) dst[d] = acc[d];
    }
}

// Kernel 2: one wave per batch. Sum 16 partials -> pooled mean -> @Wo^T + bo -> LayerNorm.
__global__ __launch_bounds__(64) void attn_pool_k2(
    const float* __restrict__ ws_part,
    const float* __restrict__ Wo, const float* __restrict__ bo,
    const float* __restrict__ gamma, const float* __restrict__ beta,
    float* __restrict__ out)
{
    const int b = blockIdx.x;
    const int f = threadIdx.x;   // 0..63, exactly one feature per lane

    float pool = 0.f;
    #pragma unroll
    for (int k = 0; k < 16; ++k) pool += ws_part[(size_t)(b * 16 + k) * 64 + f];
    pool *= (1.0f / 2500.0f);

    // y[f] = bo[f] + sum_j pooled[j] * Wo[f,j]
    float y = bo[f];
    #pragma unroll
    for (int j = 0; j < 64; ++j) {
        const float pj = __shfl(pool, j, 64);
        y = fmaf(pj, Wo[(size_t)f * 64 + j], y);
    }

    // LayerNorm over the 64 features (one full wave)
    float s1 = y;
    #pragma unroll
    for (int off = 32; off > 0; off >>= 1) s1 += __shfl_xor(s1, off, 64);
    const float mu = s1 * (1.0f / 64.0f);
    const float dlt = y - mu;
    float s2 = dlt * dlt;
    #pragma unroll
    for (int off = 32; off > 0; off >>= 1) s2 += __shfl_xor(s2, off, 64);
    const float var = s2 * (1.0f / 64.0f);

    out[(size_t)b * 64 + f] = dlt * rsqrtf(var + 1e-5f) * gamma[f] + beta[f];
}

extern "C" void kernel_launch(void* const* d_in, const int* in_sizes, int n_in,
                              void* d_out, int out_size, void* d_ws, size_t ws_size,
                              hipStream_t stream) {
    const float* sim   = (const float*)d_in[0];
    const float* wq    = (const float*)d_in[1];
    const float* bq    = (const float*)d_in[2];
    const float* wk    = (const float*)d_in[3];
    const float* bk    = (const float*)d_in[4];
    const float* wv    = (const float*)d_in[5];
    const float* bv    = (const float*)d_in[6];
    const float* pe    = (const float*)d_in[7];
    const float* Wo    = (const float*)d_in[8];
    const float* bo    = (const float*)d_in[9];
    const float* gamma = (const float*)d_in[10];
    const float* beta  = (const float*)d_in[11];
    float* ws_part = (float*)d_ws;       // needs 4096*64*4 = 1 MB
    float* out     = (float*)d_out;

    attn_pool_k1<<<dim3(1024), dim3(256), 0, stream>>>(sim, wq, bq, wk, bk, wv, bv, pe, ws_part);
    attn_pool_k2<<<dim3(256), dim3(64), 0, stream>>>(ws_part, Wo, bo, gamma, beta, out);
}

// Round 2
// 48.660 us; speedup vs baseline: 2.5949x; 2.5949x over previous
//
#include <hip/hip_runtime.h>

#define SPOS 2500
#define PER_CHUNK 625   // SPOS / 4 chunks

// Kernel 1: one thread = one position (all 8 heads). No shuffles in the hot
// loop; cross-head attention is pure register math. Per-wave partial pooled
// sums written to ws via a halving-butterfly cross-lane reduction at the end.
__global__ __launch_bounds__(256, 2) void attn_pool_k1(
    const float* __restrict__ sim,
    const float* __restrict__ wq, const float* __restrict__ bq,
    const float* __restrict__ wk, const float* __restrict__ bk,
    const float* __restrict__ wv, const float* __restrict__ bv,
    const float* __restrict__ pe,
    float* __restrict__ ws_part)
{
    const int b    = blockIdx.x >> 2;   // batch
    const int c    = blockIdx.x & 3;    // chunk of S
    const int tid  = threadIdx.x;
    const int lane = tid & 63;
    const int wave = tid >> 6;

    const float cs = 0.35355339059327373f;   // 1/sqrt(8)

    float acc[64];
    #pragma unroll
    for (int j = 0; j < 64; ++j) acc[j] = 0.f;

    const float* simb = sim + (size_t)b * SPOS;
    const int s_end = (c + 1) * PER_CHUNK;

    #pragma unroll 1
    for (int it = 0; it < 3; ++it) {
        const int s = c * PER_CHUNK + it * 256 + tid;
        if (s < s_end) {
            const float x = simb[s];

            // pe row for this position (64 floats, 16B vector loads)
            float peb[64];
            const float4* per4 = (const float4*)(pe + (size_t)s * 64);
            #pragma unroll
            for (int j = 0; j < 16; ++j) {
                const float4 t4 = per4[j];
                peb[j*4+0] = t4.x; peb[j*4+1] = t4.y;
                peb[j*4+2] = t4.z; peb[j*4+3] = t4.w;
            }

            // scores: sc[h][t] = (q_h . k_t)/sqrt(8), built d-outer so q,k
            // slices are transient (8 live at a time) -> 64 independent
            // accumulator chains, no q[64]/k[64] arrays.
            float sc[64];
            #pragma unroll
            for (int j = 0; j < 64; ++j) sc[j] = 0.f;

            #pragma unroll
            for (int d = 0; d < 8; ++d) {
                float qv[8], kv[8];
                #pragma unroll
                for (int i = 0; i < 8; ++i) {
                    const int j = i * 8 + d;
                    qv[i] = (fmaf(x, wq[j], bq[j]) + peb[j]) * cs;  // scale folded into q
                    kv[i] = fmaf(x, wk[j], bk[j]) + peb[j];
                }
                #pragma unroll
                for (int h = 0; h < 8; ++h)
                    #pragma unroll
                    for (int t = 0; t < 8; ++t)
                        sc[h*8+t] = fmaf(qv[h], kv[t], sc[h*8+t]);
            }

            // softmax per head, in place; 1/sum folded into probabilities
            #pragma unroll
            for (int h = 0; h < 8; ++h) {
                float m = sc[h*8];
                #pragma unroll
                for (int t = 1; t < 8; ++t) m = fmaxf(m, sc[h*8+t]);
                float sum = 0.f;
                #pragma unroll
                for (int t = 0; t < 8; ++t) {
                    sc[h*8+t] = __expf(sc[h*8+t] - m);
                    sum += sc[h*8+t];
                }
                const float inv = __builtin_amdgcn_rcpf(sum);
                #pragma unroll
                for (int t = 0; t < 8; ++t) sc[h*8+t] *= inv;
            }

            // PV: t-outer so v_t (8 regs) is built once per position per t
            #pragma unroll
            for (int t = 0; t < 8; ++t) {
                float vt[8];
                #pragma unroll
                for (int d = 0; d < 8; ++d)
                    vt[d] = fmaf(x, wv[t*8+d], bv[t*8+d]);
                #pragma unroll
                for (int h = 0; h < 8; ++h)
                    #pragma unroll
                    for (int d = 0; d < 8; ++d)
                        acc[h*8+d] = fmaf(sc[h*8+t], vt[d], acc[h*8+d]);
            }
        }
    }

    // Halving-butterfly: sum acc[64] across 64 lanes; register count halves
    // each stage (63 shuffles total). Lane l ends with feature bitrev6(l).
    float r32[32];
    #pragma unroll
    for (int i = 0; i < 32; ++i) {
        const bool up = (lane & 1) != 0;
        const float keep = up ? acc[i+32] : acc[i];
        const float send = up ? acc[i]    : acc[i+32];
        r32[i] = keep + __shfl_xor(send, 1, 64);
    }
    float r16[16];
    #pragma unroll
    for (int i = 0; i < 16; ++i) {
        const bool up = (lane & 2) != 0;
        const float keep = up ? r32[i+16] : r32[i];
        const float send = up ? r32[i]    : r32[i+16];
        r16[i] = keep + __shfl_xor(send, 2, 64);
    }
    float r8[8];
    #pragma unroll
    for (int i = 0; i < 8; ++i) {
        const bool up = (lane & 4) != 0;
        const float keep = up ? r16[i+8] : r16[i];
        const float send = up ? r16[i]   : r16[i+8];
        r8[i] = keep + __shfl_xor(send, 4, 64);
    }
    float r4[4];
    #pragma unroll
    for (int i = 0; i < 4; ++i) {
        const bool up = (lane & 8) != 0;
        const float keep = up ? r8[i+4] : r8[i];
        const float send = up ? r8[i]   : r8[i+4];
        r4[i] = keep + __shfl_xor(send, 8, 64);
    }
    float r2[2];
    #pragma unroll
    for (int i = 0; i < 2; ++i) {
        const bool up = (lane & 16) != 0;
        const float keep = up ? r4[i+2] : r4[i];
        const float send = up ? r4[i]   : r4[i+2];
        r2[i] = keep + __shfl_xor(send, 16, 64);
    }
    float r1;
    {
        const bool up = (lane & 32) != 0;
        const float keep = up ? r2[1] : r2[0];
        const float send = up ? r2[0] : r2[1];
        r1 = keep + __shfl_xor(send, 32, 64);
    }

    const int f = ((lane & 1) << 5) | ((lane & 2) << 3) | ((lane & 4) << 1)
                | ((lane & 8) >> 1) | ((lane & 16) >> 3) | ((lane & 32) >> 5);
    ws_part[(size_t)(blockIdx.x * 4 + wave) * 64 + f] = r1;
}

// Kernel 2: one wave per batch. Sum 16 partials -> pooled mean -> @Wo^T + bo -> LayerNorm.
__global__ __launch_bounds__(64) void attn_pool_k2(
    const float* __restrict__ ws_part,
    const float* __restrict__ Wo, const float* __restrict__ bo,
    const float* __restrict__ gamma, const float* __restrict__ beta,
    float* __restrict__ out)
{
    const int b = blockIdx.x;
    const int f = threadIdx.x;   // 0..63

    float pool = 0.f;
    #pragma unroll
    for (int k = 0; k < 16; ++k) pool += ws_part[(size_t)(b * 16 + k) * 64 + f];
    pool *= (1.0f / 2500.0f);

    float y = bo[f];
    #pragma unroll
    for (int j = 0; j < 64; ++j) {
        const float pj = __shfl(pool, j, 64);
        y = fmaf(pj, Wo[(size_t)f * 64 + j], y);
    }

    float s1 = y;
    #pragma unroll
    for (int off = 32; off > 0; off >>= 1) s1 += __shfl_xor(s1, off, 64);
    const float mu = s1 * (1.0f / 64.0f);
    const float dlt = y - mu;
    float s2 = dlt * dlt;
    #pragma unroll
    for (int off = 32; off > 0; off >>= 1) s2 += __shfl_xor(s2, off, 64);
    const float var = s2 * (1.0f / 64.0f);

    out[(size_t)b * 64 + f] = dlt * rsqrtf(var + 1e-5f) * gamma[f] + beta[f];
}

extern "C" void kernel_launch(void* const* d_in, const int* in_sizes, int n_in,
                              void* d_out, int out_size, void* d_ws, size_t ws_size,
                              hipStream_t stream) {
    const float* sim   = (const float*)d_in[0];
    const float* wq    = (const float*)d_in[1];
    const float* bq    = (const float*)d_in[2];
    const float* wk    = (const float*)d_in[3];
    const float* bk    = (const float*)d_in[4];
    const float* wv    = (const float*)d_in[5];
    const float* bv    = (const float*)d_in[6];
    const float* pe    = (const float*)d_in[7];
    const float* Wo    = (const float*)d_in[8];
    const float* bo    = (const float*)d_in[9];
    const float* gamma = (const float*)d_in[10];
    const float* beta  = (const float*)d_in[11];
    float* ws_part = (float*)d_ws;       // 1024 blocks * 4 waves * 64 f * 4 B = 1 MB
    float* out     = (float*)d_out;

    attn_pool_k1<<<dim3(1024), dim3(256), 0, stream>>>(sim, wq, bq, wk, bk, wv, bv, pe, ws_part);
    attn_pool_k2<<<dim3(256), dim3(64), 0, stream>>>(ws_part, Wo, bo, gamma, beta, out);
}

// Round 3
// 40.901 us; speedup vs baseline: 3.0871x; 1.1897x over previous
//
#include <hip/hip_runtime.h>

typedef float v2f __attribute__((ext_vector_type(2)));
#define FMA2(a,b,c) __builtin_elementwise_fma((a),(b),(c))
#define MAX2(a,b)   __builtin_elementwise_max((a),(b))

#define SPOS 2500
#define SSTRIDE 2560                 // padded column count for LC rows
#define NSLICE 8
// ws layout (floats): LC float4[32][SSTRIDE] = 327680 | A[64] | part[2048*64]
#define WS_A_OFF    (32 * SSTRIDE * 4)
#define WS_PART_OFF (WS_A_OFF + 64)
#define SCL (0.35355339059327373f * 1.4426950408889634f)   // 1/sqrt(8) * log2(e)

// Kernel 0: per (s,h) thread. Scores are quadratic in x:
//   sc[h][t] = A[h][t]*x^2 + L[h][t]*x + C[h][t]   (all pre-scaled by SCL)
// A = wq.wk (position-independent); L,C depend only on pe -> shared by all
// 256 batches (256x reuse). Stored transposed+interleaved: row j2=h*4+t2,
// column s, float4 = (L[2t2], L[2t2+1], C[2t2], C[2t2+1]).
__global__ __launch_bounds__(256) void attn_pool_k0(
    const float* __restrict__ wq, const float* __restrict__ bq,
    const float* __restrict__ wk, const float* __restrict__ bk,
    const float* __restrict__ pe, float* __restrict__ ws)
{
    const int idx = blockIdx.x * 256 + threadIdx.x;   // 0..19999
    if (idx >= SPOS * 8) return;
    const int s = idx >> 3, h = idx & 7;

    float per[64];
    const float4* p4 = (const float4*)(pe + (size_t)s * 64);
    #pragma unroll
    for (int j = 0; j < 16; ++j) {
        const float4 t = p4[j];
        per[4*j] = t.x; per[4*j+1] = t.y; per[4*j+2] = t.z; per[4*j+3] = t.w;
    }

    float eq[8];
    #pragma unroll
    for (int d = 0; d < 8; ++d) eq[d] = bq[h*8+d] + per[h*8+d];

    float Lr[8], Cr[8];
    #pragma unroll
    for (int t = 0; t < 8; ++t) {
        float l = 0.f, cc = 0.f;
        #pragma unroll
        for (int d = 0; d < 8; ++d) {
            const float ek = bk[t*8+d] + per[t*8+d];
            l  = fmaf(wq[h*8+d], ek,    l);   // wq.(bk+pe_t)
            l  = fmaf(wk[t*8+d], eq[d], l);   // wk.(bq+pe_h)
            cc = fmaf(eq[d], ek, cc);
        }
        Lr[t] = l * SCL; Cr[t] = cc * SCL;
    }

    float4* lc4 = (float4*)ws;
    #pragma unroll
    for (int t2 = 0; t2 < 4; ++t2)
        lc4[(size_t)(h*4+t2) * SSTRIDE + s] =
            make_float4(Lr[2*t2], Lr[2*t2+1], Cr[2*t2], Cr[2*t2+1]);

    if (idx < 64) {   // A[j], j = hh*8+tt
        const int hh = idx >> 3, tt = idx & 7;
        float a = 0.f;
        #pragma unroll
        for (int d = 0; d < 8; ++d) a = fmaf(wq[hh*8+d], wk[tt*8+d], a);
        ws[WS_A_OFF + idx] = a * SCL;
    }
}

// Kernel 1: thread = one position (all 8 heads), lane-parallel over positions.
// Block = 4 waves = 4 batches sharing one position slice (L1 reuse of LC).
// Packed f32 (v_pk_fma_f32) throughout; softmax in exp2 domain.
__global__ __launch_bounds__(256, 2) void attn_pool_k1(
    const float* __restrict__ sim,
    const float* __restrict__ wv, const float* __restrict__ bv,
    const float* __restrict__ ws, float* __restrict__ part)
{
    const int bg   = blockIdx.x >> 3;     // batch group 0..63
    const int sl   = blockIdx.x & 7;      // slice 0..7
    const int wave = threadIdx.x >> 6;
    const int lane = threadIdx.x & 63;
    const int b    = bg * 4 + wave;

    const int s_begin = (sl * SPOS) >> 3;
    const int s_end   = ((sl + 1) * SPOS) >> 3;   // slices of 312/313

    const float4* lc4 = (const float4*)ws;
    const v2f*    A2  = (const v2f*)(ws + WS_A_OFF);
    const float2* wv2p = (const float2*)wv;
    const float2* bv2p = (const float2*)bv;

    v2f acc2[32];
    #pragma unroll
    for (int i = 0; i < 32; ++i) acc2[i] = (v2f)(0.f);

    const float* simb = sim + (size_t)b * SPOS;

    #pragma unroll 1
    for (int it = 0; it < 5; ++it) {
        const int s = s_begin + it * 64 + lane;
        if (s < s_end) {
            const float x = simb[s];
            const v2f xx = {x, x};

            // scores: Horner  sc = (A*x + L)*x + C   (packed, 2/instr)
            v2f sc2[32];
            #pragma unroll
            for (int j2 = 0; j2 < 32; ++j2) {
                const float4 q = lc4[(size_t)j2 * SSTRIDE + s];
                const v2f lv = {q.x, q.y};
                const v2f cv = {q.z, q.w};
                sc2[j2] = FMA2(FMA2(xx, A2[j2], lv), xx, cv);
            }

            // softmax per head over t (exp2 domain; scale folded upstream)
            #pragma unroll
            for (int h = 0; h < 8; ++h) {
                const v2f m2 = MAX2(MAX2(sc2[4*h], sc2[4*h+1]),
                                    MAX2(sc2[4*h+2], sc2[4*h+3]));
                const float m = fmaxf(m2.x, m2.y);
                const v2f ms = {m, m};
                v2f den = (v2f)(0.f);
                #pragma unroll
                for (int t2 = 0; t2 < 4; ++t2) {
                    v2f e = sc2[4*h+t2] - ms;
                    e.x = exp2f(e.x);
                    e.y = exp2f(e.y);
                    sc2[4*h+t2] = e;
                    den += e;
                }
                const float inv = __builtin_amdgcn_rcpf(den.x + den.y);
                const v2f is = {inv, inv};
                #pragma unroll
                for (int t2 = 0; t2 < 4; ++t2) sc2[4*h+t2] *= is;
            }

            // PV: vt built per t (packed mul+add, 1 SGPR source each)
            #pragma unroll
            for (int t = 0; t < 8; ++t) {
                v2f vt2[4];
                #pragma unroll
                for (int d2 = 0; d2 < 4; ++d2) {
                    const float2 w2 = wv2p[t*4+d2];
                    const float2 b2 = bv2p[t*4+d2];
                    const v2f wvv = {w2.x, w2.y};
                    const v2f bvv = {b2.x, b2.y};
                    vt2[d2] = xx * wvv + bvv;
                }
                #pragma unroll
                for (int h = 0; h < 8; ++h) {
                    const v2f pp = sc2[4*h + (t >> 1)];
                    const float p = (t & 1) ? pp.y : pp.x;
                    const v2f ps = {p, p};
                    #pragma unroll
                    for (int d2 = 0; d2 < 4; ++d2)
                        acc2[h*4+d2] = FMA2(ps, vt2[d2], acc2[h*4+d2]);
                }
            }
        }
    }

    // Halving-butterfly reduction of 64 feature-partials across 64 lanes.
    // feature j lives at acc2[j>>1].x/.y
    float r32[32];
    #pragma unroll
    for (int i = 0; i < 32; ++i) {
        const float lo = (i & 1) ? acc2[i>>1].y        : acc2[i>>1].x;
        const float hi = (i & 1) ? acc2[(i>>1)+16].y   : acc2[(i>>1)+16].x;
        const bool up = (lane & 1) != 0;
        const float keep = up ? hi : lo;
        const float send = up ? lo : hi;
        r32[i] = keep + __shfl_xor(send, 1, 64);
    }
    float r16[16];
    #pragma unroll
    for (int i = 0; i < 16; ++i) {
        const bool up = (lane & 2) != 0;
        const float keep = up ? r32[i+16] : r32[i];
        const float send = up ? r32[i]    : r32[i+16];
        r16[i] = keep + __shfl_xor(send, 2, 64);
    }
    float r8[8];
    #pragma unroll
    for (int i = 0; i < 8; ++i) {
        const bool up = (lane & 4) != 0;
        const float keep = up ? r16[i+8] : r16[i];
        const float send = up ? r16[i]   : r16[i+8];
        r8[i] = keep + __shfl_xor(send, 4, 64);
    }
    float r4[4];
    #pragma unroll
    for (int i = 0; i < 4; ++i) {
        const bool up = (lane & 8) != 0;
        const float keep = up ? r8[i+4] : r8[i];
        const float send = up ? r8[i]   : r8[i+4];
        r4[i] = keep + __shfl_xor(send, 8, 64);
    }
    float r2[2];
    #pragma unroll
    for (int i = 0; i < 2; ++i) {
        const bool up = (lane & 16) != 0;
        const float keep = up ? r4[i+2] : r4[i];
        const float send = up ? r4[i]   : r4[i+2];
        r2[i] = keep + __shfl_xor(send, 16, 64);
    }
    float r1;
    {
        const bool up = (lane & 32) != 0;
        const float keep = up ? r2[1] : r2[0];
        const float send = up ? r2[0] : r2[1];
        r1 = keep + __shfl_xor(send, 32, 64);
    }

    const int f = ((lane & 1) << 5) | ((lane & 2) << 3) | ((lane & 4) << 1)
                | ((lane & 8) >> 1) | ((lane & 16) >> 3) | ((lane & 32) >> 5);
    part[(size_t)(b * NSLICE + sl) * 64 + f] = r1;
}

// Kernel 2: one wave per batch. Sum slice partials -> mean -> @Wo^T+bo -> LN.
__global__ __launch_bounds__(64) void attn_pool_k2(
    const float* __restrict__ part,
    const float* __restrict__ Wo, const float* __restrict__ bo,
    const float* __restrict__ gamma, const float* __restrict__ beta,
    float* __restrict__ out)
{
    const int b = blockIdx.x;
    const int f = threadIdx.x;

    float pool = 0.f;
    #pragma unroll
    for (int k = 0; k < NSLICE; ++k) pool += part[(size_t)(b * NSLICE + k) * 64 + f];
    pool *= (1.0f / 2500.0f);

    float y = bo[f];
    #pragma unroll
    for (int j = 0; j < 64; ++j) {
        const float pj = __shfl(pool, j, 64);
        y = fmaf(pj, Wo[(size_t)f * 64 + j], y);
    }

    float s1 = y;
    #pragma unroll
    for (int off = 32; off > 0; off >>= 1) s1 += __shfl_xor(s1, off, 64);
    const float mu = s1 * (1.0f / 64.0f);
    const float dlt = y - mu;
    float s2 = dlt * dlt;
    #pragma unroll
    for (int off = 32; off > 0; off >>= 1) s2 += __shfl_xor(s2, off, 64);
    const float var = s2 * (1.0f / 64.0f);

    out[(size_t)b * 64 + f] = dlt * rsqrtf(var + 1e-5f) * gamma[f] + beta[f];
}

extern "C" void kernel_launch(void* const* d_in, const int* in_sizes, int n_in,
                              void* d_out, int out_size, void* d_ws, size_t ws_size,
                              hipStream_t stream) {
    const float* sim   = (const float*)d_in[0];
    const float* wq    = (const float*)d_in[1];
    const float* bq    = (const float*)d_in[2];
    const float* wk    = (const float*)d_in[3];
    const float* bk    = (const float*)d_in[4];
    const float* wv    = (const float*)d_in[5];
    const float* bv    = (const float*)d_in[6];
    const float* pe    = (const float*)d_in[7];
    const float* Wo    = (const float*)d_in[8];
    const float* bo    = (const float*)d_in[9];
    const float* gamma = (const float*)d_in[10];
    const float* beta  = (const float*)d_in[11];
    float* ws   = (float*)d_ws;                 // ~1.84 MB used
    float* part = ws + WS_PART_OFF;
    float* out  = (float*)d_out;

    attn_pool_k0<<<dim3(79),  dim3(256), 0, stream>>>(wq, bq, wk, bk, pe, ws);
    attn_pool_k1<<<dim3(512), dim3(256), 0, stream>>>(sim, wv, bv, ws, part);
    attn_pool_k2<<<dim3(256), dim3(64),  0, stream>>>(part, Wo, bo, gamma, beta, out);
}

// Round 4
// 38.479 us; speedup vs baseline: 3.2814x; 1.0629x over previous
//
#include <hip/hip_runtime.h>

typedef float v2f __attribute__((ext_vector_type(2)));
#define FMA2(a,b,c) __builtin_elementwise_fma((a),(b),(c))
#define MAX2(a,b)   __builtin_elementwise_max((a),(b))

#define SPOS 2500
#define SSTRIDE 2560                 // padded column count for LC rows
#define NSLICE 8
// ws layout (floats): LC float4[32][SSTRIDE] = 327680 | A[64] | part[4096*64]
#define WS_A_OFF    (32 * SSTRIDE * 4)
#define WS_PART_OFF (WS_A_OFF + 64)
#define SCL (0.35355339059327373f * 1.4426950408889634f)   // 1/sqrt(8) * log2(e)

// Kernel 0: scores are quadratic in x: sc[h][t] = A*x^2 + L*x + C (exp2 dom).
// L,C depend only on pe -> shared by all 256 batches. Row j2 = h*4+t2,
// column s, float4 = (L[2t2], L[2t2+1], C[2t2], C[2t2+1]).
__global__ __launch_bounds__(256) void attn_pool_k0(
    const float* __restrict__ wq, const float* __restrict__ bq,
    const float* __restrict__ wk, const float* __restrict__ bk,
    const float* __restrict__ pe, float* __restrict__ ws)
{
    const int idx = blockIdx.x * 256 + threadIdx.x;   // 0..19999
    if (idx >= SPOS * 8) return;
    const int s = idx >> 3, h = idx & 7;

    float per[64];
    const float4* p4 = (const float4*)(pe + (size_t)s * 64);
    #pragma unroll
    for (int j = 0; j < 16; ++j) {
        const float4 t = p4[j];
        per[4*j] = t.x; per[4*j+1] = t.y; per[4*j+2] = t.z; per[4*j+3] = t.w;
    }

    float eq[8];
    #pragma unroll
    for (int d = 0; d < 8; ++d) eq[d] = bq[h*8+d] + per[h*8+d];

    float Lr[8], Cr[8];
    #pragma unroll
    for (int t = 0; t < 8; ++t) {
        float l = 0.f, cc = 0.f;
        #pragma unroll
        for (int d = 0; d < 8; ++d) {
            const float ek = bk[t*8+d] + per[t*8+d];
            l  = fmaf(wq[h*8+d], ek,    l);
            l  = fmaf(wk[t*8+d], eq[d], l);
            cc = fmaf(eq[d], ek, cc);
        }
        Lr[t] = l * SCL; Cr[t] = cc * SCL;
    }

    float4* lc4 = (float4*)ws;
    #pragma unroll
    for (int t2 = 0; t2 < 4; ++t2)
        lc4[(size_t)(h*4+t2) * SSTRIDE + s] =
            make_float4(Lr[2*t2], Lr[2*t2+1], Cr[2*t2], Cr[2*t2+1]);

    if (idx < 64) {
        const int hh = idx >> 3, tt = idx & 7;
        float a = 0.f;
        #pragma unroll
        for (int d = 0; d < 8; ++d) a = fmaf(wq[hh*8+d], wk[tt*8+d], a);
        ws[WS_A_OFF + idx] = a * SCL;
    }
}

// Kernel 1: wave = (batch, head-half); lane = position. Inner loop produces
// only P0[h][t] = sum_s p and P1[h][t] = sum_s x*p (PV contraction deferred
// to k2: pooled = (P1@wv + P0@bv)/S). A in SGPRs via readfirstlane.
__global__ __launch_bounds__(256, 4) void attn_pool_k1(
    const float* __restrict__ sim,
    const float* __restrict__ ws, float* __restrict__ part)
{
    const int bg   = blockIdx.x >> 3;     // 0..127
    const int sl   = blockIdx.x & 7;      // slice
    const int wave = threadIdx.x >> 6;
    const int lane = threadIdx.x & 63;
    const int b    = bg * 2 + (wave >> 1);
    const int hh   = wave & 1;            // head half: heads hh*4 .. hh*4+3

    const int s_begin = (sl * SPOS) >> 3;
    const int s_end   = ((sl + 1) * SPOS) >> 3;

    const float4* lc4 = (const float4*)ws;
    const v2f*    A2  = (const v2f*)(ws + WS_A_OFF);

    // A slice for this half -> SGPRs (readfirstlane), ~32 SGPRs not VGPRs.
    float a_s[32];
    #pragma unroll
    for (int i = 0; i < 16; ++i) {
        const v2f av = A2[hh*16 + i];
        a_s[2*i]   = __int_as_float(__builtin_amdgcn_readfirstlane(__float_as_int(av.x)));
        a_s[2*i+1] = __int_as_float(__builtin_amdgcn_readfirstlane(__float_as_int(av.y)));
    }

    v2f P0[16], P1[16];   // [hloc][t2]
    #pragma unroll
    for (int i = 0; i < 16; ++i) { P0[i] = (v2f)(0.f); P1[i] = (v2f)(0.f); }

    const float* simb = sim + (size_t)b * SPOS;

    #pragma unroll 1
    for (int it = 0; it < 5; ++it) {
        const int s = s_begin + it * 64 + lane;
        if (s < s_end) {
            const float x = simb[s];
            const v2f xx = {x, x};

            #pragma unroll
            for (int hl = 0; hl < 4; ++hl) {
                v2f e[4];
                #pragma unroll
                for (int t2 = 0; t2 < 4; ++t2) {
                    const float4 q = lc4[(size_t)(hh*16 + hl*4 + t2) * SSTRIDE + s];
                    // Horner: ((A*x + L)*x + C); first step unpacked so A can
                    // come from an SGPR (1-SGPR-per-VALU rule).
                    const float u0 = fmaf(x, a_s[hl*8 + 2*t2],     q.x);
                    const float u1 = fmaf(x, a_s[hl*8 + 2*t2 + 1], q.y);
                    const v2f uu = {u0, u1};
                    const v2f cv = {q.z, q.w};
                    e[t2] = FMA2(uu, xx, cv);
                }
                const v2f m2 = MAX2(MAX2(e[0], e[1]), MAX2(e[2], e[3]));
                const float m = fmaxf(m2.x, m2.y);
                const v2f ms = {m, m};
                v2f den2 = (v2f)(0.f);
                #pragma unroll
                for (int t2 = 0; t2 < 4; ++t2) {
                    v2f ee = e[t2] - ms;
                    ee.x = exp2f(ee.x); ee.y = exp2f(ee.y);
                    e[t2] = ee; den2 += ee;
                }
                const float inv  = __builtin_amdgcn_rcpf(den2.x + den2.y);
                const float xinv = x * inv;
                const v2f vi = {inv, inv}, vx = {xinv, xinv};
                #pragma unroll
                for (int t2 = 0; t2 < 4; ++t2) {
                    P0[hl*4+t2] = FMA2(vi, e[t2], P0[hl*4+t2]);
                    P1[hl*4+t2] = FMA2(vx, e[t2], P1[hl*4+t2]);
                }
            }
        }
    }

    // Flatten: av[i] = P0 flat (i<32, i = hloc*8+t), av[32+i] = P1 flat.
    float av[64];
    #pragma unroll
    for (int i = 0; i < 32; ++i) {
        av[i]      = (i & 1) ? P0[i >> 1].y : P0[i >> 1].x;
        av[32 + i] = (i & 1) ? P1[i >> 1].y : P1[i >> 1].x;
    }

    // Halving-butterfly across 64 lanes; lane ends with index bitrev6(lane).
    float r32[32];
    #pragma unroll
    for (int i = 0; i < 32; ++i) {
        const bool up = (lane & 1) != 0;
        const float keep = up ? av[i+32] : av[i];
        const float send = up ? av[i]    : av[i+32];
        r32[i] = keep + __shfl_xor(send, 1, 64);
    }
    float r16[16];
    #pragma unroll
    for (int i = 0; i < 16; ++i) {
        const bool up = (lane & 2) != 0;
        const float keep = up ? r32[i+16] : r32[i];
        const float send = up ? r32[i]    : r32[i+16];
        r16[i] = keep + __shfl_xor(send, 2, 64);
    }
    float r8[8];
    #pragma unroll
    for (int i = 0; i < 8; ++i) {
        const bool up = (lane & 4) != 0;
        const float keep = up ? r16[i+8] : r16[i];
        const float send = up ? r16[i]   : r16[i+8];
        r8[i] = keep + __shfl_xor(send, 4, 64);
    }
    float r4[4];
    #pragma unroll
    for (int i = 0; i < 4; ++i) {
        const bool up = (lane & 8) != 0;
        const float keep = up ? r8[i+4] : r8[i];
        const float send = up ? r8[i]   : r8[i+4];
        r4[i] = keep + __shfl_xor(send, 8, 64);
    }
    float r2[2];
    #pragma unroll
    for (int i = 0; i < 2; ++i) {
        const bool up = (lane & 16) != 0;
        const float keep = up ? r4[i+2] : r4[i];
        const float send = up ? r4[i]   : r4[i+2];
        r2[i] = keep + __shfl_xor(send, 16, 64);
    }
    float r1;
    {
        const bool up = (lane & 32) != 0;
        const float keep = up ? r2[1] : r2[0];
        const float send = up ? r2[0] : r2[1];
        r1 = keep + __shfl_xor(send, 32, 64);
    }

    const int f = ((lane & 1) << 5) | ((lane & 2) << 3) | ((lane & 4) << 1)
                | ((lane & 8) >> 1) | ((lane & 16) >> 3) | ((lane & 32) >> 5);
    part[(size_t)((b * 2 + hh) * NSLICE + sl) * 64 + f] = r1;
}

// Kernel 2: per batch: sum slice partials -> contract with wv/bv -> mean ->
// @Wo^T + bo -> LayerNorm.
__global__ __launch_bounds__(64) void attn_pool_k2(
    const float* __restrict__ part,
    const float* __restrict__ wv, const float* __restrict__ bv,
    const float* __restrict__ Wo, const float* __restrict__ bo,
    const float* __restrict__ gamma, const float* __restrict__ beta,
    float* __restrict__ out)
{
    const int b = blockIdx.x;
    const int l = threadIdx.x;           // 0..63
    const int h = l >> 3, d = l & 7;

    float v0 = 0.f, v1 = 0.f;            // flat index l of half0 / half1
    #pragma unroll
    for (int sl = 0; sl < NSLICE; ++sl) {
        v0 += part[(size_t)((b*2 + 0) * NSLICE + sl) * 64 + l];
        v1 += part[(size_t)((b*2 + 1) * NSLICE + sl) * 64 + l];
    }

    // pooled[h,d] = (sum_t P1[h][t]*wv[t,d] + P0[h][t]*bv[t,d]) / S
    float pool = 0.f;
    #pragma unroll
    for (int t = 0; t < 8; ++t) {
        const int i0 = (h & 3) * 8 + t;
        const float p0a = __shfl(v0, i0, 64),      p0b = __shfl(v1, i0, 64);
        const float p1a = __shfl(v0, i0 + 32, 64), p1b = __shfl(v1, i0 + 32, 64);
        const float p0 = (h & 4) ? p0b : p0a;
        const float p1 = (h & 4) ? p1b : p1a;
        pool = fmaf(p1, wv[t*8 + d], pool);
        pool = fmaf(p0, bv[t*8 + d], pool);
    }
    pool *= (1.0f / 2500.0f);

    float y = bo[l];
    #pragma unroll
    for (int j = 0; j < 64; ++j) {
        const float pj = __shfl(pool, j, 64);
        y = fmaf(pj, Wo[(size_t)l * 64 + j], y);
    }

    float s1 = y;
    #pragma unroll
    for (int off = 32; off > 0; off >>= 1) s1 += __shfl_xor(s1, off, 64);
    const float mu = s1 * (1.0f / 64.0f);
    const float dlt = y - mu;
    float s2 = dlt * dlt;
    #pragma unroll
    for (int off = 32; off > 0; off >>= 1) s2 += __shfl_xor(s2, off, 64);
    const float var = s2 * (1.0f / 64.0f);

    out[(size_t)b * 64 + l] = dlt * rsqrtf(var + 1e-5f) * gamma[l] + beta[l];
}

extern "C" void kernel_launch(void* const* d_in, const int* in_sizes, int n_in,
                              void* d_out, int out_size, void* d_ws, size_t ws_size,
                              hipStream_t stream) {
    const float* sim   = (const float*)d_in[0];
    const float* wq    = (const float*)d_in[1];
    const float* bq    = (const float*)d_in[2];
    const float* wk    = (const float*)d_in[3];
    const float* bk    = (const float*)d_in[4];
    const float* wv    = (const float*)d_in[5];
    const float* bv    = (const float*)d_in[6];
    const float* pe    = (const float*)d_in[7];
    const float* Wo    = (const float*)d_in[8];
    const float* bo    = (const float*)d_in[9];
    const float* gamma = (const float*)d_in[10];
    const float* beta  = (const float*)d_in[11];
    float* ws   = (float*)d_ws;                 // ~2.4 MB used
    float* part = ws + WS_PART_OFF;
    float* out  = (float*)d_out;

    attn_pool_k0<<<dim3(79),   dim3(256), 0, stream>>>(wq, bq, wk, bk, pe, ws);
    attn_pool_k1<<<dim3(1024), dim3(256), 0, stream>>>(sim, ws, part);
    attn_pool_k2<<<dim3(256),  dim3(64),  0, stream>>>(part, wv, bv, Wo, bo, gamma, beta, out);
}

// Round 5
// 32.589 us; speedup vs baseline: 3.8745x; 1.1807x over previous
//
#include <hip/hip_runtime.h>

typedef float v2f __attribute__((ext_vector_type(2)));
#define FMA2(a,b,c) __builtin_elementwise_fma((a),(b),(c))
#define MAX2(a,b)   __builtin_elementwise_max((a),(b))

#define SPOS 2500
#define SSTRIDE 2560                 // padded column count for LC rows
#define NSLICE 8
// ws layout (floats): LC float4[32][SSTRIDE] | A[64] | WoT[4096] | part[256*8*8*16]
#define WS_A_OFF    (32 * SSTRIDE * 4)
#define WS_WOT_OFF  (WS_A_OFF + 64)
#define WS_PART_OFF (WS_WOT_OFF + 4096)
#define SCL (0.35355339059327373f * 1.4426950408889634f)   // 1/sqrt(8) * log2(e)

// Kernel 0: scores are quadratic in x: sc[h][t] = A*x^2 + L*x + C (exp2 dom).
// L,C depend only on pe -> shared by all 256 batches. Row j2 = h*4+t2,
// column s, float4 = (L[2t2], L[2t2+1], C[2t2], C[2t2+1]).
// Also: A[64] and WoT (Wo transposed, for coalesced k2 loads).
__global__ __launch_bounds__(256) void attn_pool_k0(
    const float* __restrict__ wq, const float* __restrict__ bq,
    const float* __restrict__ wk, const float* __restrict__ bk,
    const float* __restrict__ pe, const float* __restrict__ Wo,
    float* __restrict__ ws)
{
    const int idx = blockIdx.x * 256 + threadIdx.x;   // 0..24575

    if (idx < SPOS * 8) {
        const int s = idx >> 3, h = idx & 7;

        float per[64];
        const float4* p4 = (const float4*)(pe + (size_t)s * 64);
        #pragma unroll
        for (int j = 0; j < 16; ++j) {
            const float4 t = p4[j];
            per[4*j] = t.x; per[4*j+1] = t.y; per[4*j+2] = t.z; per[4*j+3] = t.w;
        }

        float eq[8];
        #pragma unroll
        for (int d = 0; d < 8; ++d) eq[d] = bq[h*8+d] + per[h*8+d];

        float Lr[8], Cr[8];
        #pragma unroll
        for (int t = 0; t < 8; ++t) {
            float l = 0.f, cc = 0.f;
            #pragma unroll
            for (int d = 0; d < 8; ++d) {
                const float ek = bk[t*8+d] + per[t*8+d];
                l  = fmaf(wq[h*8+d], ek,    l);
                l  = fmaf(wk[t*8+d], eq[d], l);
                cc = fmaf(eq[d], ek, cc);
            }
            Lr[t] = l * SCL; Cr[t] = cc * SCL;
        }

        float4* lc4 = (float4*)ws;
        #pragma unroll
        for (int t2 = 0; t2 < 4; ++t2)
            lc4[(size_t)(h*4+t2) * SSTRIDE + s] =
                make_float4(Lr[2*t2], Lr[2*t2+1], Cr[2*t2], Cr[2*t2+1]);

        if (idx < 64) {
            const int hh = idx >> 3, tt = idx & 7;
            float a = 0.f;
            #pragma unroll
            for (int d = 0; d < 8; ++d) a = fmaf(wq[hh*8+d], wk[tt*8+d], a);
            ws[WS_A_OFF + idx] = a * SCL;
        }
    } else if (idx >= 20480 && idx < 20480 + 4096) {
        const int i = idx - 20480;          // i = j*64 + f
        const int j = i >> 6, f = i & 63;
        ws[WS_WOT_OFF + i] = Wo[(size_t)f * 64 + j];   // WoT[j][f]
    }
}

// Kernel 1: wave = (one head, 4-batch group); lane = position. Each LC float4
// is reused by 4 batches (register-held). Accumulates only
// P0[nb][t] = sum_s p, P1[nb][t] = sum_s x*p. ~115 VGPR, no min-waves force.
__global__ __launch_bounds__(256) void attn_pool_k1(
    const float* __restrict__ sim,
    const float* __restrict__ ws, float* __restrict__ part)
{
    const int bg   = blockIdx.x >> 4;          // 0..63: batches bg*4..bg*4+3
    const int sl   = (blockIdx.x >> 1) & 7;    // slice 0..7
    const int hq   = blockIdx.x & 1;
    const int wave = threadIdx.x >> 6;
    const int lane = threadIdx.x & 63;
    const int h    = hq * 4 + wave;            // head 0..7

    const int s_begin = (sl * SPOS) >> 3;
    const int s_end   = ((sl + 1) * SPOS) >> 3;   // slices of 312/313

    const float4* lch = (const float4*)ws + (size_t)(h * 4) * SSTRIDE;

    // A row for this head -> 8 SGPRs
    float aA[8];
    #pragma unroll
    for (int i = 0; i < 8; ++i)
        aA[i] = __int_as_float(__builtin_amdgcn_readfirstlane(
                    __float_as_int(ws[WS_A_OFF + h * 8 + i])));

    v2f P0[16], P1[16];   // [nb][t2]
    #pragma unroll
    for (int i = 0; i < 16; ++i) { P0[i] = (v2f)(0.f); P1[i] = (v2f)(0.f); }

    const float* simb = sim + (size_t)(bg * 4) * SPOS;

    #pragma unroll 1
    for (int it = 0; it < 5; ++it) {
        const int s = s_begin + it * 64 + lane;
        if (s < s_end) {
            float4 q[4];
            #pragma unroll
            for (int t2 = 0; t2 < 4; ++t2) q[t2] = lch[t2 * SSTRIDE + s];
            float xb[4];
            #pragma unroll
            for (int nb = 0; nb < 4; ++nb) xb[nb] = simb[nb * SPOS + s];

            #pragma unroll
            for (int nb = 0; nb < 4; ++nb) {
                const float x = xb[nb];
                const v2f xx = {x, x};
                v2f e[4];
                #pragma unroll
                for (int t2 = 0; t2 < 4; ++t2) {
                    // Horner ((A*x + L)*x + C); first step scalar so A stays SGPR
                    const float u0 = fmaf(x, aA[2*t2],   q[t2].x);
                    const float u1 = fmaf(x, aA[2*t2+1], q[t2].y);
                    const v2f uu = {u0, u1};
                    const v2f cv = {q[t2].z, q[t2].w};
                    e[t2] = FMA2(uu, xx, cv);
                }
                const v2f m2 = MAX2(MAX2(e[0], e[1]), MAX2(e[2], e[3]));
                const float m = fmaxf(m2.x, m2.y);
                const v2f ms = {m, m};
                v2f den2 = (v2f)(0.f);
                #pragma unroll
                for (int t2 = 0; t2 < 4; ++t2) {
                    v2f ee = e[t2] - ms;
                    ee.x = exp2f(ee.x); ee.y = exp2f(ee.y);
                    e[t2] = ee; den2 += ee;
                }
                const float inv  = __builtin_amdgcn_rcpf(den2.x + den2.y);
                const float xinv = x * inv;
                const v2f vi = {inv, inv}, vx = {xinv, xinv};
                #pragma unroll
                for (int t2 = 0; t2 < 4; ++t2) {
                    P0[nb*4+t2] = FMA2(vi, e[t2], P0[nb*4+t2]);
                    P1[nb*4+t2] = FMA2(vx, e[t2], P1[nb*4+t2]);
                }
            }
        }
    }

    // Flatten: av[nb*16 + t] = P0[nb][t], av[nb*16 + 8 + t] = P1[nb][t]
    float av[64];
    #pragma unroll
    for (int nb = 0; nb < 4; ++nb)
        #pragma unroll
        for (int t = 0; t < 8; ++t) {
            av[nb*16 + t]     = (t & 1) ? P0[nb*4 + (t>>1)].y : P0[nb*4 + (t>>1)].x;
            av[nb*16 + 8 + t] = (t & 1) ? P1[nb*4 + (t>>1)].y : P1[nb*4 + (t>>1)].x;
        }

    // Halving-butterfly across 64 lanes; lane ends with index bitrev6(lane).
    float r32[32];
    #pragma unroll
    for (int i = 0; i < 32; ++i) {
        const bool up = (lane & 1) != 0;
        const float keep = up ? av[i+32] : av[i];
        const float send = up ? av[i]    : av[i+32];
        r32[i] = keep + __shfl_xor(send, 1, 64);
    }
    float r16[16];
    #pragma unroll
    for (int i = 0; i < 16; ++i) {
        const bool up = (lane & 2) != 0;
        const float keep = up ? r32[i+16] : r32[i];
        const float send = up ? r32[i]    : r32[i+16];
        r16[i] = keep + __shfl_xor(send, 2, 64);
    }
    float r8[8];
    #pragma unroll
    for (int i = 0; i < 8; ++i) {
        const bool up = (lane & 4) != 0;
        const float keep = up ? r16[i+8] : r16[i];
        const float send = up ? r16[i]   : r16[i+8];
        r8[i] = keep + __shfl_xor(send, 4, 64);
    }
    float r4[4];
    #pragma unroll
    for (int i = 0; i < 4; ++i) {
        const bool up = (lane & 8) != 0;
        const float keep = up ? r8[i+4] : r8[i];
        const float send = up ? r8[i]   : r8[i+4];
        r4[i] = keep + __shfl_xor(send, 8, 64);
    }
    float r2[2];
    #pragma unroll
    for (int i = 0; i < 2; ++i) {
        const bool up = (lane & 16) != 0;
        const float keep = up ? r4[i+2] : r4[i];
        const float send = up ? r4[i]   : r4[i+2];
        r2[i] = keep + __shfl_xor(send, 16, 64);
    }
    float r1;
    {
        const bool up = (lane & 32) != 0;
        const float keep = up ? r2[1] : r2[0];
        const float send = up ? r2[0] : r2[1];
        r1 = keep + __shfl_xor(send, 32, 64);
    }

    const int f = ((lane & 1) << 5) | ((lane & 2) << 3) | ((lane & 4) << 1)
                | ((lane & 8) >> 1) | ((lane & 16) >> 3) | ((lane & 32) >> 5);
    const int nb = f >> 4, rem = f & 15;
    part[(((size_t)(bg*4 + nb) * 8 + h) * NSLICE + sl) * 16 + rem] = r1;
}

// Kernel 2: per batch: sum slice partials -> contract with wv/bv -> mean ->
// @Wo^T (coalesced via WoT) + bo -> LayerNorm.
__global__ __launch_bounds__(64) void attn_pool_k2(
    const float* __restrict__ ws,
    const float* __restrict__ wv, const float* __restrict__ bv,
    const float* __restrict__ bo,
    const float* __restrict__ gamma, const float* __restrict__ beta,
    float* __restrict__ out)
{
    const float* part = ws + WS_PART_OFF;
    const float* WoT  = ws + WS_WOT_OFF;
    const int b = blockIdx.x;
    const int l = threadIdx.x;           // as (h,t) for partials, (h,d) for pooled
    const int h = l >> 3, t = l & 7, d = t;

    float p0 = 0.f, p1 = 0.f;            // P0[h][t], P1[h][t]
    #pragma unroll
    for (int sl = 0; sl < NSLICE; ++sl) {
        const size_t base = (((size_t)b * 8 + h) * NSLICE + sl) * 16;
        p0 += part[base + t];
        p1 += part[base + 8 + t];
    }

    // pooled[h,d] = (sum_t P1[h][t]*wv[t,d] + P0[h][t]*bv[t,d]) / S
    float pool = 0.f;
    #pragma unroll
    for (int tt = 0; tt < 8; ++tt) {
        const float P1v = __shfl(p1, h*8 + tt, 64);
        const float P0v = __shfl(p0, h*8 + tt, 64);
        pool = fmaf(P1v, wv[tt*8 + d], pool);
        pool = fmaf(P0v, bv[tt*8 + d], pool);
    }
    pool *= (1.0f / 2500.0f);

    float y = bo[l];
    #pragma unroll
    for (int j = 0; j < 64; ++j) {
        const float pj = __shfl(pool, j, 64);
        y = fmaf(pj, WoT[j * 64 + l], y);     // coalesced across lanes
    }

    float s1 = y;
    #pragma unroll
    for (int off = 32; off > 0; off >>= 1) s1 += __shfl_xor(s1, off, 64);
    const float mu = s1 * (1.0f / 64.0f);
    const float dlt = y - mu;
    float s2 = dlt * dlt;
    #pragma unroll
    for (int off = 32; off > 0; off >>= 1) s2 += __shfl_xor(s2, off, 64);
    const float var = s2 * (1.0f / 64.0f);

    out[(size_t)b * 64 + l] = dlt * rsqrtf(var + 1e-5f) * gamma[l] + beta[l];
}

extern "C" void kernel_launch(void* const* d_in, const int* in_sizes, int n_in,
                              void* d_out, int out_size, void* d_ws, size_t ws_size,
                              hipStream_t stream) {
    const float* sim   = (const float*)d_in[0];
    const float* wq    = (const float*)d_in[1];
    const float* bq    = (const float*)d_in[2];
    const float* wk    = (const float*)d_in[3];
    const float* bk    = (const float*)d_in[4];
    const float* wv    = (const float*)d_in[5];
    const float* bv    = (const float*)d_in[6];
    const float* pe    = (const float*)d_in[7];
    const float* Wo    = (const float*)d_in[8];
    const float* bo    = (const float*)d_in[9];
    const float* gamma = (const float*)d_in[10];
    const float* beta  = (const float*)d_in[11];
    float* ws   = (float*)d_ws;                 // ~2.4 MB used
    float* part = ws + WS_PART_OFF;
    float* out  = (float*)d_out;

    attn_pool_k0<<<dim3(96),   dim3(256), 0, stream>>>(wq, bq, wk, bk, pe, Wo, ws);
    attn_pool_k1<<<dim3(1024), dim3(256), 0, stream>>>(sim, ws, part);
    attn_pool_k2<<<dim3(256),  dim3(64),  0, stream>>>(ws, wv, bv, bo, gamma, beta, out);
}